// Round 3
// baseline (216.828 us; speedup 1.0000x reference)
//
#include <hip/hip_runtime.h>
#include <hip/hip_bf16.h>
#include <math.h>

// Problem constants
#define B_    8
#define T_    2048
#define NTOK  (B_ * T_)   // 16384 tokens
#define D_    512
#define E_    8
#define CAP   NTOK        // per-expert bucket capacity (worst case)
#define RT_TB 32          // router tokens per 256-thread block

typedef __attribute__((ext_vector_type(4))) float f32x4;
typedef __attribute__((ext_vector_type(8))) short short8;  // 8 bf16 (MFMA a/b frag)

__device__ __forceinline__ void async_load16(const void* g, void* l) {
    __builtin_amdgcn_global_load_lds(
        (const __attribute__((address_space(1))) unsigned int*)g,
        (__attribute__((address_space(3))) unsigned int*)l,
        16, 0, 0);
}

__device__ __forceinline__ f32x4 fma4(f32x4 a, f32x4 b, f32x4 c) {
    c.x = fmaf(a.x, b.x, c.x); c.y = fmaf(a.y, b.y, c.y);
    c.z = fmaf(a.z, b.z, c.z); c.w = fmaf(a.w, b.w, c.w);
    return c;
}

// ---------------------------------------------------------------------------
// Kernel 1: Wk[e][d][h] fp32 -> Wkt[e][h][d] bf16 (B^T layout for GEMM),
// plus (z==E_ slice) Wr/Wn [D][E] -> [E][D] fp32 for the router's L1-friendly
// row-contiguous reads.
// ---------------------------------------------------------------------------
__global__ __launch_bounds__(256) void transpose_wk(
    const float* __restrict__ Wk, __hip_bfloat16* __restrict__ Wkt,
    const float* __restrict__ Wr, const float* __restrict__ Wn,
    float* __restrict__ WrT, float* __restrict__ WnT)
{
    const int tid = threadIdx.y * 32 + threadIdx.x;
    if (blockIdx.z == E_) {  // router-weight transpose slice
        const int flat = blockIdx.y * 16 + blockIdx.x;
        if (flat < 16) {
            const int idx = flat * 256 + tid;  // [0, 4096)
            const int d = idx >> 3, e = idx & 7;
            WrT[e * D_ + d] = Wr[d * E_ + e];
            WnT[e * D_ + d] = Wn[d * E_ + e];
        }
        return;
    }
    __shared__ float tile[32][33];
    const int e  = blockIdx.z;
    const int d0 = blockIdx.x * 32;
    const int h0 = blockIdx.y * 32;
    const int tx = threadIdx.x, ty = threadIdx.y;

    const float* src = Wk + ((size_t)e * D_ + d0) * D_ + h0;
    #pragma unroll
    for (int r = ty; r < 32; r += 8)
        tile[r][tx] = src[(size_t)r * D_ + tx];
    __syncthreads();
    __hip_bfloat16* dst = Wkt + ((size_t)e * D_ + h0) * D_ + d0;
    #pragma unroll
    for (int r = ty; r < 32; r += 8)
        dst[(size_t)r * D_ + tx] = __float2bfloat16(tile[tx][r]);
}

// ---------------------------------------------------------------------------
// top-2 merge of two sorted (v1,i1,v2,i2) states; lax.top_k tie semantics
// (higher value first; equal values -> lower index first).
// ---------------------------------------------------------------------------
__device__ __forceinline__ void merge_top2(float& v1, int& i1, float& v2, int& i2,
                                           float u1, int j1, float u2, int j2) {
    const bool a_first = (v1 > u1) || (v1 == u1 && i1 < j1);
    float t1, t2; int k1, k2;
    if (a_first) {
        t1 = v1; k1 = i1;
        const bool s = (v2 > u1) || (v2 == u1 && i2 < j1);
        t2 = s ? v2 : u1; k2 = s ? i2 : j1;
    } else {
        t1 = u1; k1 = j1;
        const bool s = (u2 > v1) || (u2 == v1 && j2 < i1);
        t2 = s ? u2 : v1; k2 = s ? j2 : i1;
    }
    v1 = t1; i1 = k1; v2 = t2; i2 = k2;
}

// ---------------------------------------------------------------------------
// Kernel 2: router. R2's wave-per-token butterfly measured ~2600 VALU
// instrs/token (72% VALUBusy @48us) -- the 16-acc x 6-step shuffle tree
// dominated. v3: lane = one (token, expert) output, full K=512 walk per
// lane, NO cross-lane dot reduction. 8 tokens/wave; x via 8-lane-broadcast
// dwordx4 (L2-hot from the fused bf16-convert pass), W rows L1-resident.
// fp32 throughout (bf16 router could flip near-tied top-2 picks).
// ---------------------------------------------------------------------------
__global__ __launch_bounds__(256) void router_kernel(
    const float* __restrict__ x,     // [NTOK][D]
    const float* __restrict__ eps,   // [NTOK][E]
    const float* __restrict__ WrT,   // [E][D]
    const float* __restrict__ br,    // [E]
    const float* __restrict__ WnT,   // [E][D]
    const float* __restrict__ bn,    // [E]
    __hip_bfloat16* __restrict__ xb, // out: [NTOK][D] bf16
    uint4* __restrict__ top2)        // out: [NTOK] {i1|i2<<8, g1bits, g2bits, 0}
{
    const int tid  = threadIdx.x;
    const int tok0 = blockIdx.x * RT_TB;

    // Pass 1: fused x -> bf16 conversion (flat, coalesced). Independent of
    // pass 2; no barrier needed.
    {
        const float* src = x + (size_t)tok0 * D_;
        __hip_bfloat16* dst = xb + (size_t)tok0 * D_;
        #pragma unroll
        for (int it = 0; it < (RT_TB * D_) / (256 * 4); ++it) {
            const int i = (it * 256 + tid) * 4;
            const f32x4 v = *(const f32x4*)(src + i);
            union { __hip_bfloat16 h[4]; uint2 u; } cv;
            cv.h[0] = __float2bfloat16(v.x);
            cv.h[1] = __float2bfloat16(v.y);
            cv.h[2] = __float2bfloat16(v.z);
            cv.h[3] = __float2bfloat16(v.w);
            *(uint2*)(dst + i) = cv.u;
        }
    }

    // Pass 2: dots. lane -> (token tl, expert e); both R and N accumulators.
    const int lane = tid & 63;
    const int tl   = (tid >> 6) * 8 + (lane >> 3);
    const int e    = lane & 7;
    const int tok  = tok0 + tl;

    const float* xr = x + (size_t)tok * D_;
    const float* wr = WrT + e * D_;
    const float* wn = WnT + e * D_;
    f32x4 aR0 = {0,0,0,0}, aR1 = {0,0,0,0}, aN0 = {0,0,0,0}, aN1 = {0,0,0,0};
    #pragma unroll 4
    for (int d = 0; d < D_; d += 8) {
        const f32x4 x0 = *(const f32x4*)(xr + d);
        const f32x4 x1 = *(const f32x4*)(xr + d + 4);
        const f32x4 r0 = *(const f32x4*)(wr + d);
        const f32x4 r1 = *(const f32x4*)(wr + d + 4);
        const f32x4 n0 = *(const f32x4*)(wn + d);
        const f32x4 n1 = *(const f32x4*)(wn + d + 4);
        aR0 = fma4(x0, r0, aR0); aR1 = fma4(x1, r1, aR1);
        aN0 = fma4(x0, n0, aN0); aN1 = fma4(x1, n1, aN1);
    }
    const float rdot = ((aR0.x + aR0.y) + (aR0.z + aR0.w))
                     + ((aR1.x + aR1.y) + (aR1.z + aR1.w));
    const float ndot = ((aN0.x + aN0.y) + (aN0.z + aN0.w))
                     + ((aN1.x + aN1.y) + (aN1.z + aN1.w));

    const float nl = ndot + bn[e];
    // jax.nn.softplus = max(z,0) + log1p(exp(-|z|))
    const float sp = fmaxf(nl, 0.f) + log1pf(expf(-fabsf(nl)));
    const float noisy = rdot + br[e] + eps[(size_t)tok * E_ + e] * sp;

    // top-2 across the 8 expert lanes of this token (butterfly xor 1,2,4)
    float v1 = noisy; int i1 = e;
    float v2 = -3.4e38f; int i2 = 999;
    #pragma unroll
    for (int off = 1; off < 8; off <<= 1) {
        const float u1 = __shfl_xor(v1, off);
        const int   j1 = __shfl_xor(i1, off);
        const float u2 = __shfl_xor(v2, off);
        const int   j2 = __shfl_xor(i2, off);
        merge_top2(v1, i1, v2, i2, u1, j1, u2, j2);
    }

    if (e == 0) {
        const float t  = expf(v2 - v1);  // v2 <= v1
        const float g1 = 1.f / (1.f + t);
        const float g2 = t / (1.f + t);
        top2[tok] = make_uint4((unsigned)i1 | ((unsigned)i2 << 8),
                               __float_as_uint(g1), __float_as_uint(g2), 0u);
    }
}

// ---------------------------------------------------------------------------
// Kernel 3: bucket build. LDS histogram -> 8 global atomics per block.
// Entry: {tok | slot<<31, gate_bits}; slot = contribution plane.
// ---------------------------------------------------------------------------
__global__ __launch_bounds__(256) void bucket_kernel(
    const uint4* __restrict__ top2,
    int* __restrict__ counts,     // [E] pre-zeroed
    uint2* __restrict__ entries)  // [E][CAP]
{
    __shared__ int hist[E_];
    __shared__ int base[E_];
    const int tid = threadIdx.x;
    const int tok = blockIdx.x * 256 + tid;
    if (tid < E_) hist[tid] = 0;
    __syncthreads();
    const uint4 t = top2[tok];
    const int i1 = t.x & 0xff, i2 = (t.x >> 8) & 0xff;
    const int l1 = atomicAdd(&hist[i1], 1);
    const int l2 = atomicAdd(&hist[i2], 1);
    __syncthreads();
    if (tid < E_) base[tid] = atomicAdd(counts + tid, hist[tid]);
    __syncthreads();
    entries[(size_t)i1 * CAP + base[i1] + l1] = make_uint2((unsigned)tok, t.y);
    entries[(size_t)i2 * CAP + base[i2] + l2] =
        make_uint2((unsigned)tok | 0x80000000u, t.z);
}

// ---------------------------------------------------------------------------
// Kernel 4: grouped expert GEMM. 128x128 tile, BK=32, 4 waves of 4x4
// mfma_f32_16x16x32_bf16, global_load_lds(16B) staging.
// Epilogue (slots): plain stores of g*(acc+bk) into BF16 slot planes
// (halves combine traffic vs fp32; ~1e-3 absmax cost, budget 0.0387).
// ---------------------------------------------------------------------------
__global__ __launch_bounds__(256) void moe_gemm(
    const __hip_bfloat16* __restrict__ xb,   // [NTOK][D] bf16
    const __hip_bfloat16* __restrict__ wkt,  // [E][D(out)][D(in)] bf16 (B^T)
    const float* __restrict__ bk,            // [E][D]
    const int* __restrict__ counts,          // [E]
    const uint2* __restrict__ entries,       // [E][CAP]
    __hip_bfloat16* __restrict__ outg,       // [2][NTOK][D] bf16 slot planes
    float* __restrict__ out,                 // [NTOK][D] fp32 (atomic fallback)
    int use_slots)
{
    constexpr int BM = 128, BN = 128, BK = 32;
    __shared__ __hip_bfloat16 As[BM * BK];
    __shared__ __hip_bfloat16 Bs[BN * BK];
    __shared__ uint2 ent[BM];

    const int e  = blockIdx.z;
    const int mt = blockIdx.y;
    const int nt = blockIdx.x;
    const int cnt = counts[e];
    if (mt * BM >= cnt) return;

    const int tid = threadIdx.x;
    const int wave = tid >> 6, lane = tid & 63;

    if (tid < BM) {
        const int idx = mt * BM + tid;
        ent[tid] = (idx < cnt) ? entries[(size_t)e * CAP + idx] : make_uint2(0u, 0u);
    }
    __syncthreads();

    const int quad = lane >> 4, lr = lane & 15;
    const int wm = wave >> 1, wn = wave & 1;
    const int sub = lane >> 2, part = lane & 3;

    f32x4 acc[4][4];
    #pragma unroll
    for (int i = 0; i < 4; ++i)
        #pragma unroll
        for (int j = 0; j < 4; ++j) acc[i][j] = (f32x4){0.f, 0.f, 0.f, 0.f};

    const size_t tok0 = ent[wave * 32 + sub].x & 0x7fffffffu;
    const size_t tok1 = ent[wave * 32 + 16 + sub].x & 0x7fffffffu;
    const size_t brow0 = (size_t)e * D_ + nt * BN + wave * 32 + sub;

    for (int k0 = 0; k0 < D_; k0 += BK) {
        async_load16(xb + tok0 * D_ + k0 + part * 8, As + (wave * 32) * BK);
        async_load16(xb + tok1 * D_ + k0 + part * 8, As + (wave * 32 + 16) * BK);
        async_load16(wkt + brow0 * D_ + k0 + part * 8, Bs + (wave * 32) * BK);
        async_load16(wkt + (brow0 + 16) * D_ + k0 + part * 8, Bs + (wave * 32 + 16) * BK);
        __syncthreads();

        short8 a[4], b[4];
        #pragma unroll
        for (int i = 0; i < 4; ++i)
            a[i] = *(const short8*)(As + (wm * 64 + i * 16 + lr) * BK + quad * 8);
        #pragma unroll
        for (int j = 0; j < 4; ++j)
            b[j] = *(const short8*)(Bs + (wn * 64 + j * 16 + lr) * BK + quad * 8);
        #pragma unroll
        for (int i = 0; i < 4; ++i)
            #pragma unroll
            for (int j = 0; j < 4; ++j)
                acc[i][j] = __builtin_amdgcn_mfma_f32_16x16x32_bf16(a[i], b[j], acc[i][j], 0, 0, 0);
        __syncthreads();
    }

    const int colbase = nt * BN + wn * 64 + lr;
    float bkv[4];
    #pragma unroll
    for (int j = 0; j < 4; ++j) bkv[j] = bk[e * D_ + colbase + j * 16];

    #pragma unroll
    for (int i = 0; i < 4; ++i) {
        #pragma unroll
        for (int r = 0; r < 4; ++r) {
            const int row = wm * 64 + i * 16 + quad * 4 + r;  // C: row = quad*4+reg
            if (mt * BM + row < cnt) {
                const uint2 en = ent[row];
                const unsigned ts = en.x;
                const float g = __uint_as_float(en.y);
                if (use_slots) {
                    __hip_bfloat16* orow = outg + ((size_t)(ts >> 31) * NTOK
                                          + (ts & 0x7fffffffu)) * D_ + colbase;
                    #pragma unroll
                    for (int j = 0; j < 4; ++j)
                        orow[j * 16] = __float2bfloat16(g * (acc[i][j][r] + bkv[j]));
                } else {
                    float* orow = out + (size_t)(ts & 0x7fffffffu) * D_ + colbase;
                    #pragma unroll
                    for (int j = 0; j < 4; ++j)
                        atomicAdd(orow + j * 16, g * (acc[i][j][r] + bkv[j]));
                }
            }
        }
    }
}

// ---------------------------------------------------------------------------
// Kernel 5: combine the two bf16 slot planes -> fp32 d_out. 8 elems/thread.
// ---------------------------------------------------------------------------
__global__ __launch_bounds__(256) void combine_kernel(
    const __hip_bfloat16* __restrict__ outg, float* __restrict__ out)
{
    const size_t i = ((size_t)blockIdx.x * 256 + threadIdx.x) * 8;
    const uint4 u0 = *(const uint4*)(outg + i);
    const uint4 u1 = *(const uint4*)(outg + (size_t)NTOK * D_ + i);
    const unsigned* a = (const unsigned*)&u0;
    const unsigned* b = (const unsigned*)&u1;
    float o[8];
    #pragma unroll
    for (int k = 0; k < 4; ++k) {
        o[2*k]   = __uint_as_float(a[k] << 16) + __uint_as_float(b[k] << 16);
        o[2*k+1] = __uint_as_float(a[k] & 0xffff0000u)
                 + __uint_as_float(b[k] & 0xffff0000u);
    }
    *(f32x4*)(out + i)     = *(f32x4*)(o);
    *(f32x4*)(out + i + 4) = *(f32x4*)(o + 4);
}

// ---------------------------------------------------------------------------
// Launch
// ---------------------------------------------------------------------------
extern "C" void kernel_launch(void* const* d_in, const int* in_sizes, int n_in,
                              void* d_out, int out_size, void* d_ws, size_t ws_size,
                              hipStream_t stream) {
    const float* x   = (const float*)d_in[0];
    const float* eps = (const float*)d_in[1];
    const float* Wr  = (const float*)d_in[2];
    const float* br  = (const float*)d_in[3];
    const float* Wn  = (const float*)d_in[4];
    const float* bn  = (const float*)d_in[5];
    const float* Wk  = (const float*)d_in[6];
    const float* bk  = (const float*)d_in[7];
    float* out = (float*)d_out;

    // workspace layout (256B-aligned)
    char* ws = (char*)d_ws;
    size_t off = 0;
    int* counts = (int*)(ws + off);                    off += 256;
    uint2* entries = (uint2*)(ws + off);               off += (size_t)E_ * CAP * 8;      // 1 MiB
    __hip_bfloat16* xb = (__hip_bfloat16*)(ws + off);  off += (size_t)NTOK * D_ * 2;     // 16 MiB
    __hip_bfloat16* wkt = (__hip_bfloat16*)(ws + off); off += (size_t)E_ * D_ * D_ * 2;  // 4 MiB
    float* WrT = (float*)(ws + off);                   off += (size_t)E_ * D_ * 4;       // 16 KiB
    float* WnT = (float*)(ws + off);                   off += (size_t)E_ * D_ * 4;       // 16 KiB
    uint4* top2 = (uint4*)(ws + off);                  off += (size_t)NTOK * 16;         // 256 KiB
    __hip_bfloat16* outg = (__hip_bfloat16*)(ws + off); off += (size_t)2 * NTOK * D_ * 2; // 32 MiB
    const int use_slots = (ws_size >= off) ? 1 : 0;

    hipMemsetAsync(counts, 0, E_ * sizeof(int), stream);
    if (!use_slots)
        hipMemsetAsync(out, 0, (size_t)out_size * sizeof(float), stream);

    transpose_wk<<<dim3(16, 16, E_ + 1), dim3(32, 8), 0, stream>>>(
        Wk, wkt, Wr, Wn, WrT, WnT);
    router_kernel<<<dim3(NTOK / RT_TB), dim3(256), 0, stream>>>(
        x, eps, WrT, br, WnT, bn, xb, top2);
    bucket_kernel<<<dim3(NTOK / 256), dim3(256), 0, stream>>>(top2, counts, entries);
    moe_gemm<<<dim3(D_ / 128, CAP / 128, E_), dim3(256), 0, stream>>>(
        xb, wkt, bk, counts, entries, outg, out, use_slots);
    if (use_slots)
        combine_kernel<<<dim3((NTOK * D_) / (256 * 8)), dim3(256), 0, stream>>>(outg, out);
}

// Round 4
// 210.795 us; speedup vs baseline: 1.0286x; 1.0286x over previous
//
#include <hip/hip_runtime.h>
#include <hip/hip_bf16.h>
#include <math.h>

// Problem constants
#define B_    8
#define T_    2048
#define NTOK  (B_ * T_)   // 16384 tokens
#define D_    512
#define E_    8
#define CAP   NTOK        // per-expert bucket capacity (worst case)
#define RT_TOK 16         // router tokens per block
#define RT_THR 128        // router threads per block (2 waves)
#define XPAD  516         // padded LDS row stride (floats): banks (4*tl+d)%32 disjoint

typedef __attribute__((ext_vector_type(4))) float f32x4;
typedef __attribute__((ext_vector_type(8))) short short8;  // 8 bf16 (MFMA a/b frag)

__device__ __forceinline__ void async_load16(const void* g, void* l) {
    __builtin_amdgcn_global_load_lds(
        (const __attribute__((address_space(1))) unsigned int*)g,
        (__attribute__((address_space(3))) unsigned int*)l,
        16, 0, 0);
}

__device__ __forceinline__ f32x4 fma4(f32x4 a, f32x4 b, f32x4 c) {
    c.x = fmaf(a.x, b.x, c.x); c.y = fmaf(a.y, b.y, c.y);
    c.z = fmaf(a.z, b.z, c.z); c.w = fmaf(a.w, b.w, c.w);
    return c;
}

// ---------------------------------------------------------------------------
// Kernel 1: Wk[e][d][h] fp32 -> Wkt[e][h][d] bf16 (B^T layout for GEMM),
// plus (z==E_ slice) Wr/Wn [D][E] -> [E][D] fp32 for router row reads.
// ---------------------------------------------------------------------------
__global__ __launch_bounds__(256) void transpose_wk(
    const float* __restrict__ Wk, __hip_bfloat16* __restrict__ Wkt,
    const float* __restrict__ Wr, const float* __restrict__ Wn,
    float* __restrict__ WrT, float* __restrict__ WnT)
{
    const int tid = threadIdx.y * 32 + threadIdx.x;
    if (blockIdx.z == E_) {
        const int flat = blockIdx.y * 16 + blockIdx.x;
        if (flat < 16) {
            const int idx = flat * 256 + tid;  // [0, 4096)
            const int d = idx >> 3, e = idx & 7;
            WrT[e * D_ + d] = Wr[d * E_ + e];
            WnT[e * D_ + d] = Wn[d * E_ + e];
        }
        return;
    }
    __shared__ float tile[32][33];
    const int e  = blockIdx.z;
    const int d0 = blockIdx.x * 32;
    const int h0 = blockIdx.y * 32;
    const int tx = threadIdx.x, ty = threadIdx.y;

    const float* src = Wk + ((size_t)e * D_ + d0) * D_ + h0;
    #pragma unroll
    for (int r = ty; r < 32; r += 8)
        tile[r][tx] = src[(size_t)r * D_ + tx];
    __syncthreads();
    __hip_bfloat16* dst = Wkt + ((size_t)e * D_ + h0) * D_ + d0;
    #pragma unroll
    for (int r = ty; r < 32; r += 8)
        dst[(size_t)r * D_ + tx] = __float2bfloat16(tile[tx][r]);
}

// ---------------------------------------------------------------------------
// top-2 merge, lax.top_k tie semantics (equal values -> lower index first).
// ---------------------------------------------------------------------------
__device__ __forceinline__ void merge_top2(float& v1, int& i1, float& v2, int& i2,
                                           float u1, int j1, float u2, int j2) {
    const bool a_first = (v1 > u1) || (v1 == u1 && i1 < j1);
    float t1, t2; int k1, k2;
    if (a_first) {
        t1 = v1; k1 = i1;
        const bool s = (v2 > u1) || (v2 == u1 && i2 < j1);
        t2 = s ? v2 : u1; k2 = s ? i2 : j1;
    } else {
        t1 = u1; k1 = j1;
        const bool s = (u2 > v1) || (u2 == v1 && j2 < i1);
        t2 = s ? u2 : v1; k2 = s ? j2 : i1;
    }
    v1 = t1; i1 = k1; v2 = t2; i2 = k2;
}

// ---------------------------------------------------------------------------
// Kernel 2: router v4.
// R2 failed on issue rate (scattered W loads, 16-acc butterfly: 72% VALU @48us).
// R3 failed on latency (2048 waves, dependent global-load chain: 8% VALU @76us).
// v4: lane = (token, expert), K=512 walk fed from LDS:
//  - stage: coalesced global x -> padded LDS tile, FUSED with bf16 convert
//    (x read from HBM exactly once)
//  - dot: x via ds_read_b128 (8 expert lanes same addr = broadcast; padded
//    stride 516 puts the 8 token-groups on disjoint banks), W rows from L1
//    (8 lanes same addr = merged). fp32 throughout (top-2 flip safety).
// 1024 blocks x 128 thr, 33KB LDS -> 4 blocks/CU co-resident.
// ---------------------------------------------------------------------------
__global__ __launch_bounds__(RT_THR) void router_kernel(
    const float* __restrict__ x,     // [NTOK][D]
    const float* __restrict__ eps,   // [NTOK][E]
    const float* __restrict__ WrT,   // [E][D]
    const float* __restrict__ br,    // [E]
    const float* __restrict__ WnT,   // [E][D]
    const float* __restrict__ bn,    // [E]
    __hip_bfloat16* __restrict__ xb, // out: [NTOK][D] bf16
    uint4* __restrict__ top2)        // out: [NTOK] {i1|i2<<8, g1bits, g2bits, 0}
{
    __shared__ float xs[RT_TOK * XPAD];  // 33 KB
    const int tid  = threadIdx.x;
    const int tok0 = blockIdx.x * RT_TOK;

    // Stage + fused convert: 8 iters x (2 global dwordx4 in, 2 ds_write_b128,
    // 1 dwordx4 bf16 out). Flat f covers [0, RT_TOK*D_).
    {
        const float* src = x + (size_t)tok0 * D_;
        __hip_bfloat16* dst = xb + (size_t)tok0 * D_;
        #pragma unroll
        for (int it = 0; it < (RT_TOK * D_) / (RT_THR * 8); ++it) {
            const int f = (it * RT_THR + tid) * 8;
            const f32x4 v0 = *(const f32x4*)(src + f);
            const f32x4 v1 = *(const f32x4*)(src + f + 4);
            const int t = f >> 9, d = f & (D_ - 1);
            *(f32x4*)(xs + t * XPAD + d)     = v0;
            *(f32x4*)(xs + t * XPAD + d + 4) = v1;
            union { __hip_bfloat16 h[8]; uint4 u; } cv;
            cv.h[0] = __float2bfloat16(v0.x); cv.h[1] = __float2bfloat16(v0.y);
            cv.h[2] = __float2bfloat16(v0.z); cv.h[3] = __float2bfloat16(v0.w);
            cv.h[4] = __float2bfloat16(v1.x); cv.h[5] = __float2bfloat16(v1.y);
            cv.h[6] = __float2bfloat16(v1.z); cv.h[7] = __float2bfloat16(v1.w);
            *(uint4*)(dst + f) = cv.u;
        }
    }
    __syncthreads();

    // Dot pass: thread -> (token tl, expert e).
    const int lane = tid & 63;
    const int tl   = (tid >> 6) * 8 + (lane >> 3);  // [0, 16)
    const int e    = lane & 7;
    const int tok  = tok0 + tl;

    const float* xr = xs + tl * XPAD;   // LDS
    const float* wr = WrT + e * D_;     // global, L1-hot
    const float* wn = WnT + e * D_;
    f32x4 aR0 = {0,0,0,0}, aR1 = {0,0,0,0}, aN0 = {0,0,0,0}, aN1 = {0,0,0,0};
    #pragma unroll 4
    for (int d = 0; d < D_; d += 8) {
        const f32x4 x0 = *(const f32x4*)(xr + d);
        const f32x4 x1 = *(const f32x4*)(xr + d + 4);
        const f32x4 r0 = *(const f32x4*)(wr + d);
        const f32x4 r1 = *(const f32x4*)(wr + d + 4);
        const f32x4 n0 = *(const f32x4*)(wn + d);
        const f32x4 n1 = *(const f32x4*)(wn + d + 4);
        aR0 = fma4(x0, r0, aR0); aR1 = fma4(x1, r1, aR1);
        aN0 = fma4(x0, n0, aN0); aN1 = fma4(x1, n1, aN1);
    }
    const float rdot = ((aR0.x + aR0.y) + (aR0.z + aR0.w))
                     + ((aR1.x + aR1.y) + (aR1.z + aR1.w));
    const float ndot = ((aN0.x + aN0.y) + (aN0.z + aN0.w))
                     + ((aN1.x + aN1.y) + (aN1.z + aN1.w));

    const float nl = ndot + bn[e];
    const float sp = fmaxf(nl, 0.f) + log1pf(expf(-fabsf(nl)));  // exact softplus
    const float noisy = rdot + br[e] + eps[(size_t)tok * E_ + e] * sp;

    // top-2 across the 8 expert lanes (butterfly xor 1,2,4)
    float v1 = noisy; int i1 = e;
    float v2 = -3.4e38f; int i2 = 999;
    #pragma unroll
    for (int off = 1; off < 8; off <<= 1) {
        const float u1 = __shfl_xor(v1, off);
        const int   j1 = __shfl_xor(i1, off);
        const float u2 = __shfl_xor(v2, off);
        const int   j2 = __shfl_xor(i2, off);
        merge_top2(v1, i1, v2, i2, u1, j1, u2, j2);
    }

    if (e == 0) {
        const float t  = expf(v2 - v1);  // v2 <= v1
        const float g1 = 1.f / (1.f + t);
        const float g2 = t / (1.f + t);
        top2[tok] = make_uint4((unsigned)i1 | ((unsigned)i2 << 8),
                               __float_as_uint(g1), __float_as_uint(g2), 0u);
    }
}

// ---------------------------------------------------------------------------
// Kernel 3: bucket build. LDS histogram -> 8 global atomics per block.
// Entry: {tok | slot<<31, gate_bits}; slot = contribution plane.
// ---------------------------------------------------------------------------
__global__ __launch_bounds__(256) void bucket_kernel(
    const uint4* __restrict__ top2,
    int* __restrict__ counts,     // [E] pre-zeroed
    uint2* __restrict__ entries)  // [E][CAP]
{
    __shared__ int hist[E_];
    __shared__ int base[E_];
    const int tid = threadIdx.x;
    const int tok = blockIdx.x * 256 + tid;
    if (tid < E_) hist[tid] = 0;
    __syncthreads();
    const uint4 t = top2[tok];
    const int i1 = t.x & 0xff, i2 = (t.x >> 8) & 0xff;
    const int l1 = atomicAdd(&hist[i1], 1);
    const int l2 = atomicAdd(&hist[i2], 1);
    __syncthreads();
    if (tid < E_) base[tid] = atomicAdd(counts + tid, hist[tid]);
    __syncthreads();
    entries[(size_t)i1 * CAP + base[i1] + l1] = make_uint2((unsigned)tok, t.y);
    entries[(size_t)i2 * CAP + base[i2] + l2] =
        make_uint2((unsigned)tok | 0x80000000u, t.z);
}

// ---------------------------------------------------------------------------
// Kernel 4: grouped expert GEMM. 128x128 tile, BK=32, 4 waves of 4x4
// mfma_f32_16x16x32_bf16, global_load_lds(16B) staging. Epilogue: plain
// stores of g*(acc+bk) into bf16 slot planes; combine sums them.
// ---------------------------------------------------------------------------
__global__ __launch_bounds__(256) void moe_gemm(
    const __hip_bfloat16* __restrict__ xb,   // [NTOK][D] bf16
    const __hip_bfloat16* __restrict__ wkt,  // [E][D(out)][D(in)] bf16 (B^T)
    const float* __restrict__ bk,            // [E][D]
    const int* __restrict__ counts,          // [E]
    const uint2* __restrict__ entries,       // [E][CAP]
    __hip_bfloat16* __restrict__ outg,       // [2][NTOK][D] bf16 slot planes
    float* __restrict__ out,                 // [NTOK][D] fp32 (atomic fallback)
    int use_slots)
{
    constexpr int BM = 128, BN = 128, BK = 32;
    __shared__ __hip_bfloat16 As[BM * BK];
    __shared__ __hip_bfloat16 Bs[BN * BK];
    __shared__ uint2 ent[BM];

    const int e  = blockIdx.z;
    const int mt = blockIdx.y;
    const int nt = blockIdx.x;
    const int cnt = counts[e];
    if (mt * BM >= cnt) return;

    const int tid = threadIdx.x;
    const int wave = tid >> 6, lane = tid & 63;

    if (tid < BM) {
        const int idx = mt * BM + tid;
        ent[tid] = (idx < cnt) ? entries[(size_t)e * CAP + idx] : make_uint2(0u, 0u);
    }
    __syncthreads();

    const int quad = lane >> 4, lr = lane & 15;
    const int wm = wave >> 1, wn = wave & 1;
    const int sub = lane >> 2, part = lane & 3;

    f32x4 acc[4][4];
    #pragma unroll
    for (int i = 0; i < 4; ++i)
        #pragma unroll
        for (int j = 0; j < 4; ++j) acc[i][j] = (f32x4){0.f, 0.f, 0.f, 0.f};

    const size_t tok0 = ent[wave * 32 + sub].x & 0x7fffffffu;
    const size_t tok1 = ent[wave * 32 + 16 + sub].x & 0x7fffffffu;
    const size_t brow0 = (size_t)e * D_ + nt * BN + wave * 32 + sub;

    for (int k0 = 0; k0 < D_; k0 += BK) {
        async_load16(xb + tok0 * D_ + k0 + part * 8, As + (wave * 32) * BK);
        async_load16(xb + tok1 * D_ + k0 + part * 8, As + (wave * 32 + 16) * BK);
        async_load16(wkt + brow0 * D_ + k0 + part * 8, Bs + (wave * 32) * BK);
        async_load16(wkt + (brow0 + 16) * D_ + k0 + part * 8, Bs + (wave * 32 + 16) * BK);
        __syncthreads();

        short8 a[4], b[4];
        #pragma unroll
        for (int i = 0; i < 4; ++i)
            a[i] = *(const short8*)(As + (wm * 64 + i * 16 + lr) * BK + quad * 8);
        #pragma unroll
        for (int j = 0; j < 4; ++j)
            b[j] = *(const short8*)(Bs + (wn * 64 + j * 16 + lr) * BK + quad * 8);
        #pragma unroll
        for (int i = 0; i < 4; ++i)
            #pragma unroll
            for (int j = 0; j < 4; ++j)
                acc[i][j] = __builtin_amdgcn_mfma_f32_16x16x32_bf16(a[i], b[j], acc[i][j], 0, 0, 0);
        __syncthreads();
    }

    const int colbase = nt * BN + wn * 64 + lr;
    float bkv[4];
    #pragma unroll
    for (int j = 0; j < 4; ++j) bkv[j] = bk[e * D_ + colbase + j * 16];

    #pragma unroll
    for (int i = 0; i < 4; ++i) {
        #pragma unroll
        for (int r = 0; r < 4; ++r) {
            const int row = wm * 64 + i * 16 + quad * 4 + r;  // C: row = quad*4+reg
            if (mt * BM + row < cnt) {
                const uint2 en = ent[row];
                const unsigned ts = en.x;
                const float g = __uint_as_float(en.y);
                if (use_slots) {
                    __hip_bfloat16* orow = outg + ((size_t)(ts >> 31) * NTOK
                                          + (ts & 0x7fffffffu)) * D_ + colbase;
                    #pragma unroll
                    for (int j = 0; j < 4; ++j)
                        orow[j * 16] = __float2bfloat16(g * (acc[i][j][r] + bkv[j]));
                } else {
                    float* orow = out + (size_t)(ts & 0x7fffffffu) * D_ + colbase;
                    #pragma unroll
                    for (int j = 0; j < 4; ++j)
                        atomicAdd(orow + j * 16, g * (acc[i][j][r] + bkv[j]));
                }
            }
        }
    }
}

// ---------------------------------------------------------------------------
// Kernel 5: combine the two bf16 slot planes -> fp32 d_out. 8 elems/thread.
// ---------------------------------------------------------------------------
__global__ __launch_bounds__(256) void combine_kernel(
    const __hip_bfloat16* __restrict__ outg, float* __restrict__ out)
{
    const size_t i = ((size_t)blockIdx.x * 256 + threadIdx.x) * 8;
    const uint4 u0 = *(const uint4*)(outg + i);
    const uint4 u1 = *(const uint4*)(outg + (size_t)NTOK * D_ + i);
    const unsigned* a = (const unsigned*)&u0;
    const unsigned* b = (const unsigned*)&u1;
    float o[8];
    #pragma unroll
    for (int k = 0; k < 4; ++k) {
        o[2*k]   = __uint_as_float(a[k] << 16) + __uint_as_float(b[k] << 16);
        o[2*k+1] = __uint_as_float(a[k] & 0xffff0000u)
                 + __uint_as_float(b[k] & 0xffff0000u);
    }
    *(f32x4*)(out + i)     = *(f32x4*)(o);
    *(f32x4*)(out + i + 4) = *(f32x4*)(o + 4);
}

// ---------------------------------------------------------------------------
// Launch
// ---------------------------------------------------------------------------
extern "C" void kernel_launch(void* const* d_in, const int* in_sizes, int n_in,
                              void* d_out, int out_size, void* d_ws, size_t ws_size,
                              hipStream_t stream) {
    const float* x   = (const float*)d_in[0];
    const float* eps = (const float*)d_in[1];
    const float* Wr  = (const float*)d_in[2];
    const float* br  = (const float*)d_in[3];
    const float* Wn  = (const float*)d_in[4];
    const float* bn  = (const float*)d_in[5];
    const float* Wk  = (const float*)d_in[6];
    const float* bk  = (const float*)d_in[7];
    float* out = (float*)d_out;

    // workspace layout (256B-aligned)
    char* ws = (char*)d_ws;
    size_t off = 0;
    int* counts = (int*)(ws + off);                    off += 256;
    uint2* entries = (uint2*)(ws + off);               off += (size_t)E_ * CAP * 8;      // 1 MiB
    __hip_bfloat16* xb = (__hip_bfloat16*)(ws + off);  off += (size_t)NTOK * D_ * 2;     // 16 MiB
    __hip_bfloat16* wkt = (__hip_bfloat16*)(ws + off); off += (size_t)E_ * D_ * D_ * 2;  // 4 MiB
    float* WrT = (float*)(ws + off);                   off += (size_t)E_ * D_ * 4;       // 16 KiB
    float* WnT = (float*)(ws + off);                   off += (size_t)E_ * D_ * 4;       // 16 KiB
    uint4* top2 = (uint4*)(ws + off);                  off += (size_t)NTOK * 16;         // 256 KiB
    __hip_bfloat16* outg = (__hip_bfloat16*)(ws + off); off += (size_t)2 * NTOK * D_ * 2; // 32 MiB
    const int use_slots = (ws_size >= off) ? 1 : 0;

    hipMemsetAsync(counts, 0, E_ * sizeof(int), stream);
    if (!use_slots)
        hipMemsetAsync(out, 0, (size_t)out_size * sizeof(float), stream);

    transpose_wk<<<dim3(16, 16, E_ + 1), dim3(32, 8), 0, stream>>>(
        Wk, wkt, Wr, Wn, WrT, WnT);
    router_kernel<<<dim3(NTOK / RT_TOK), dim3(RT_THR), 0, stream>>>(
        x, eps, WrT, br, WnT, bn, xb, top2);
    bucket_kernel<<<dim3(NTOK / 256), dim3(256), 0, stream>>>(top2, counts, entries);
    moe_gemm<<<dim3(D_ / 128, CAP / 128, E_), dim3(256), 0, stream>>>(
        xb, wkt, bk, counts, entries, outg, out, use_slots);
    if (use_slots)
        combine_kernel<<<dim3((NTOK * D_) / (256 * 8)), dim3(256), 0, stream>>>(outg, out);
}

// Round 5
// 175.898 us; speedup vs baseline: 1.2327x; 1.1984x over previous
//
#include <hip/hip_runtime.h>
#include <hip/hip_bf16.h>
#include <math.h>

// Problem constants
#define B_    8
#define T_    2048
#define NTOK  (B_ * T_)   // 16384 tokens
#define D_    512
#define E_    8
#define CAP   NTOK        // per-expert bucket capacity (worst case)

// router v5 geometry: 512 blocks x 256 thr; 32 tok/block, 8 tok/wave,
// lane = (kidx 0..15) x (ts 0..3); each lane: 2 tokens, 512/16=32 k-values.
#define RV_TOK    32
#define RV_THR    256
#define XS_STRIDE 132     // fp32 row stride for x tile: <=2-way LDS conflicts
#define WS_FLOATS 2108    // 128*16 + 15*4 skew + last row

typedef __attribute__((ext_vector_type(4))) float f32x4;
typedef __attribute__((ext_vector_type(8))) short short8;  // 8 bf16 (MFMA a/b frag)

__device__ __forceinline__ void async_load16(const void* g, void* l) {
    __builtin_amdgcn_global_load_lds(
        (const __attribute__((address_space(1))) unsigned int*)g,
        (__attribute__((address_space(3))) unsigned int*)l,
        16, 0, 0);
}

// ---------------------------------------------------------------------------
// Kernel 1: Wk[e][d][h] fp32 -> Wkt[e][h][d] bf16 (B^T layout for GEMM).
// ---------------------------------------------------------------------------
__global__ __launch_bounds__(256) void transpose_wk(
    const float* __restrict__ Wk, __hip_bfloat16* __restrict__ Wkt)
{
    __shared__ float tile[32][33];
    const int e  = blockIdx.z;
    const int d0 = blockIdx.x * 32;
    const int h0 = blockIdx.y * 32;
    const int tx = threadIdx.x, ty = threadIdx.y;

    const float* src = Wk + ((size_t)e * D_ + d0) * D_ + h0;
    #pragma unroll
    for (int r = ty; r < 32; r += 8)
        tile[r][tx] = src[(size_t)r * D_ + tx];
    __syncthreads();
    __hip_bfloat16* dst = Wkt + ((size_t)e * D_ + h0) * D_ + d0;
    #pragma unroll
    for (int r = ty; r < 32; r += 8)
        dst[(size_t)r * D_ + tx] = __float2bfloat16(tile[tx][r]);
}

// ---------------------------------------------------------------------------
// Kernel 2: router v5.
// Postmortems: R2 issue-bound (20x VALU bloat), R3/R4 latency-bound (too few
// waves: 8/CU with 1-2 waves/SIMD and load-chained loops).
// v5: 2048 waves (8/CU), lane = 2 tokens x 16-way k-split. Per k: one 64B
// LDS W-row read (skewed: conflict-free) amortized over 32 fp32 FMAs
// -> VALU:LDS cyc = 1024:430 per wave-chunk, VALU-bound.
// x: global->LDS staged coalesced, fused bf16 convert (HBM read exactly once).
// W: staged per 128-k chunk straight from Wr/Wn (no prep pass).
// fp32 fma throughout (bf16 router could flip near-tied top-2 sets).
// ---------------------------------------------------------------------------
__global__ __launch_bounds__(RV_THR) void router_kernel(
    const float* __restrict__ x,     // [NTOK][D]
    const float* __restrict__ eps,   // [NTOK][E]
    const float* __restrict__ Wr,    // [D][E]
    const float* __restrict__ br,    // [E]
    const float* __restrict__ Wn,    // [D][E]
    const float* __restrict__ bn,    // [E]
    __hip_bfloat16* __restrict__ xb, // out: [NTOK][D] bf16
    uint4* __restrict__ top2)        // out: [NTOK] {i1|i2<<8, g1bits, g2bits}
{
    __shared__ float xs[RV_TOK * XS_STRIDE];  // 16.9 KB
    __shared__ float wsh[WS_FLOATS];          // 8.4 KB; row k at k*16+(k>>3)*4

    const int tid  = threadIdx.x;
    const int tok0 = blockIdx.x * RV_TOK;
    const int lane = tid & 63, wv = tid >> 6;
    const int kidx = lane >> 2, ts = lane & 3;
    const int ta = wv * 8 + ts, tb = ta + 4;   // this lane's 2 block-tokens
    const int wk = tid >> 1, wh = tid & 1;     // W stager: row, half

    float accA[16], accB[16];  // [0..7]=x.Wr per expert, [8..15]=x.Wn
    #pragma unroll
    for (int c = 0; c < 16; ++c) { accA[c] = 0.f; accB[c] = 0.f; }

    for (int kc = 0; kc < D_; kc += 128) {
        // stage x chunk [32 tok][128 k] + fused bf16 convert/store
        #pragma unroll
        for (int it = 0; it < 4; ++it) {
            const int f   = it * RV_THR + tid;      // f32x4 index in [0,1024)
            const int row = f >> 5, col = (f & 31) * 4;
            const f32x4 v = *(const f32x4*)(x + (size_t)(tok0 + row) * D_ + kc + col);
            *(f32x4*)(xs + row * XS_STRIDE + col) = v;
            union { __hip_bfloat16 h[4]; uint2 u; } cv;
            cv.h[0] = __float2bfloat16(v.x); cv.h[1] = __float2bfloat16(v.y);
            cv.h[2] = __float2bfloat16(v.z); cv.h[3] = __float2bfloat16(v.w);
            *(uint2*)(xb + (size_t)(tok0 + row) * D_ + kc + col) = cv.u;
        }
        // stage W chunk [128 k][16 c] skewed; cols 0-7 = Wr, 8-15 = Wn
        {
            const float* src = (wh ? Wn : Wr) + (size_t)(kc + wk) * E_;
            const f32x4 w0 = *(const f32x4*)(src);
            const f32x4 w1 = *(const f32x4*)(src + 4);
            float* dst = wsh + wk * 16 + (wk >> 3) * 4 + wh * 8;
            *(f32x4*)(dst)     = w0;
            *(f32x4*)(dst + 4) = w1;
        }
        __syncthreads();

        // compute: this lane's 8 k-values of the chunk (k = kidx*8 + kk)
        const float* xra = xs + ta * XS_STRIDE + kidx * 8;
        const float* xrb = xs + tb * XS_STRIDE + kidx * 8;
        const f32x4 xa0 = *(const f32x4*)(xra);
        const f32x4 xa1 = *(const f32x4*)(xra + 4);
        const f32x4 xc0 = *(const f32x4*)(xrb);
        const f32x4 xc1 = *(const f32x4*)(xrb + 4);
        const float* wbase = wsh + kidx * 132;  // (kidx*8)*16 + kidx*4
        #pragma unroll
        for (int kk = 0; kk < 8; ++kk) {
            const float xav = (kk < 4) ? xa0[kk] : xa1[kk - 4];
            const float xbv = (kk < 4) ? xc0[kk] : xc1[kk - 4];
            const float* wrow = wbase + kk * 16;
            #pragma unroll
            for (int c4 = 0; c4 < 4; ++c4) {
                const f32x4 w = *(const f32x4*)(wrow + c4 * 4);
                #pragma unroll
                for (int c = 0; c < 4; ++c) {
                    accA[c4 * 4 + c] = fmaf(xav, w[c], accA[c4 * 4 + c]);
                    accB[c4 * 4 + c] = fmaf(xbv, w[c], accB[c4 * 4 + c]);
                }
            }
        }
        __syncthreads();
    }

    // reduce across the 16 kidx lanes (stride 4): xor 4,8,16,32
    #pragma unroll
    for (int off = 4; off < 64; off <<= 1) {
        #pragma unroll
        for (int c = 0; c < 16; ++c) {
            accA[c] += __shfl_xor(accA[c], off);
            accB[c] += __shfl_xor(accB[c], off);
        }
    }

    if (lane < 4) {  // kidx==0 lanes hold full dots for tokens ta, tb
        #pragma unroll
        for (int half = 0; half < 2; ++half) {
            const int tok = tok0 + (half ? tb : ta);
            float nv[8];
            #pragma unroll
            for (int e = 0; e < 8; ++e) {
                const float rd = half ? accB[e] : accA[e];
                const float nd = half ? accB[8 + e] : accA[8 + e];
                const float nl = nd + bn[e];
                // jax.nn.softplus = max(z,0) + log1p(exp(-|z|))
                const float sp = fmaxf(nl, 0.f) + log1pf(expf(-fabsf(nl)));
                nv[e] = rd + br[e] + eps[(size_t)tok * E_ + e] * sp;
            }
            // top-2, lax.top_k tie semantics (lowest index wins ties)
            int i1 = 0; float v1 = nv[0];
            #pragma unroll
            for (int e = 1; e < 8; ++e)
                if (nv[e] > v1) { v1 = nv[e]; i1 = e; }
            int i2 = -1; float v2 = -3.4e38f;
            #pragma unroll
            for (int e = 0; e < 8; ++e)
                if (e != i1 && nv[e] > v2) { v2 = nv[e]; i2 = e; }
            const float t  = expf(v2 - v1);
            const float g1 = 1.f / (1.f + t);
            const float g2 = t / (1.f + t);
            top2[tok] = make_uint4((unsigned)i1 | ((unsigned)i2 << 8),
                                   __float_as_uint(g1), __float_as_uint(g2), 0u);
        }
    }
}

// ---------------------------------------------------------------------------
// Kernel 3: bucket build. LDS histogram -> 8 global atomics per block.
// Entry: {tok | slot<<31, gate_bits}; slot = contribution plane.
// ---------------------------------------------------------------------------
__global__ __launch_bounds__(256) void bucket_kernel(
    const uint4* __restrict__ top2,
    int* __restrict__ counts,     // [E] pre-zeroed
    uint2* __restrict__ entries)  // [E][CAP]
{
    __shared__ int hist[E_];
    __shared__ int base[E_];
    const int tid = threadIdx.x;
    const int tok = blockIdx.x * 256 + tid;
    if (tid < E_) hist[tid] = 0;
    __syncthreads();
    const uint4 t = top2[tok];
    const int i1 = t.x & 0xff, i2 = (t.x >> 8) & 0xff;
    const int l1 = atomicAdd(&hist[i1], 1);
    const int l2 = atomicAdd(&hist[i2], 1);
    __syncthreads();
    if (tid < E_) base[tid] = atomicAdd(counts + tid, hist[tid]);
    __syncthreads();
    entries[(size_t)i1 * CAP + base[i1] + l1] = make_uint2((unsigned)tok, t.y);
    entries[(size_t)i2 * CAP + base[i2] + l2] =
        make_uint2((unsigned)tok | 0x80000000u, t.z);
}

// ---------------------------------------------------------------------------
// Kernel 4: grouped expert GEMM. 128x128 tile, BK=32, 4 waves of 4x4
// mfma_f32_16x16x32_bf16, global_load_lds(16B) staging. Epilogue: plain
// stores of g*(acc+bk) into bf16 slot planes; combine sums them.
// ---------------------------------------------------------------------------
__global__ __launch_bounds__(256) void moe_gemm(
    const __hip_bfloat16* __restrict__ xb,   // [NTOK][D] bf16
    const __hip_bfloat16* __restrict__ wkt,  // [E][D(out)][D(in)] bf16 (B^T)
    const float* __restrict__ bk,            // [E][D]
    const int* __restrict__ counts,          // [E]
    const uint2* __restrict__ entries,       // [E][CAP]
    __hip_bfloat16* __restrict__ outg,       // [2][NTOK][D] bf16 slot planes
    float* __restrict__ out,                 // [NTOK][D] fp32 (atomic fallback)
    int use_slots)
{
    constexpr int BM = 128, BN = 128, BK = 32;
    __shared__ __hip_bfloat16 As[BM * BK];
    __shared__ __hip_bfloat16 Bs[BN * BK];
    __shared__ uint2 ent[BM];

    const int e  = blockIdx.z;
    const int mt = blockIdx.y;
    const int nt = blockIdx.x;
    const int cnt = counts[e];
    if (mt * BM >= cnt) return;

    const int tid = threadIdx.x;
    const int wave = tid >> 6, lane = tid & 63;

    if (tid < BM) {
        const int idx = mt * BM + tid;
        ent[tid] = (idx < cnt) ? entries[(size_t)e * CAP + idx] : make_uint2(0u, 0u);
    }
    __syncthreads();

    const int quad = lane >> 4, lr = lane & 15;
    const int wm = wave >> 1, wn = wave & 1;
    const int sub = lane >> 2, part = lane & 3;

    f32x4 acc[4][4];
    #pragma unroll
    for (int i = 0; i < 4; ++i)
        #pragma unroll
        for (int j = 0; j < 4; ++j) acc[i][j] = (f32x4){0.f, 0.f, 0.f, 0.f};

    const size_t tok0 = ent[wave * 32 + sub].x & 0x7fffffffu;
    const size_t tok1 = ent[wave * 32 + 16 + sub].x & 0x7fffffffu;
    const size_t brow0 = (size_t)e * D_ + nt * BN + wave * 32 + sub;

    for (int k0 = 0; k0 < D_; k0 += BK) {
        async_load16(xb + tok0 * D_ + k0 + part * 8, As + (wave * 32) * BK);
        async_load16(xb + tok1 * D_ + k0 + part * 8, As + (wave * 32 + 16) * BK);
        async_load16(wkt + brow0 * D_ + k0 + part * 8, Bs + (wave * 32) * BK);
        async_load16(wkt + (brow0 + 16) * D_ + k0 + part * 8, Bs + (wave * 32 + 16) * BK);
        __syncthreads();

        short8 a[4], b[4];
        #pragma unroll
        for (int i = 0; i < 4; ++i)
            a[i] = *(const short8*)(As + (wm * 64 + i * 16 + lr) * BK + quad * 8);
        #pragma unroll
        for (int j = 0; j < 4; ++j)
            b[j] = *(const short8*)(Bs + (wn * 64 + j * 16 + lr) * BK + quad * 8);
        #pragma unroll
        for (int i = 0; i < 4; ++i)
            #pragma unroll
            for (int j = 0; j < 4; ++j)
                acc[i][j] = __builtin_amdgcn_mfma_f32_16x16x32_bf16(a[i], b[j], acc[i][j], 0, 0, 0);
        __syncthreads();
    }

    const int colbase = nt * BN + wn * 64 + lr;
    float bkv[4];
    #pragma unroll
    for (int j = 0; j < 4; ++j) bkv[j] = bk[e * D_ + colbase + j * 16];

    #pragma unroll
    for (int i = 0; i < 4; ++i) {
        #pragma unroll
        for (int r = 0; r < 4; ++r) {
            const int row = wm * 64 + i * 16 + quad * 4 + r;  // C: row = quad*4+reg
            if (mt * BM + row < cnt) {
                const uint2 en = ent[row];
                const unsigned ts2 = en.x;
                const float g = __uint_as_float(en.y);
                if (use_slots) {
                    __hip_bfloat16* orow = outg + ((size_t)(ts2 >> 31) * NTOK
                                          + (ts2 & 0x7fffffffu)) * D_ + colbase;
                    #pragma unroll
                    for (int j = 0; j < 4; ++j)
                        orow[j * 16] = __float2bfloat16(g * (acc[i][j][r] + bkv[j]));
                } else {
                    float* orow = out + (size_t)(ts2 & 0x7fffffffu) * D_ + colbase;
                    #pragma unroll
                    for (int j = 0; j < 4; ++j)
                        atomicAdd(orow + j * 16, g * (acc[i][j][r] + bkv[j]));
                }
            }
        }
    }
}

// ---------------------------------------------------------------------------
// Kernel 5: combine the two bf16 slot planes -> fp32 d_out. 8 elems/thread.
// ---------------------------------------------------------------------------
__global__ __launch_bounds__(256) void combine_kernel(
    const __hip_bfloat16* __restrict__ outg, float* __restrict__ out)
{
    const size_t i = ((size_t)blockIdx.x * 256 + threadIdx.x) * 8;
    const uint4 u0 = *(const uint4*)(outg + i);
    const uint4 u1 = *(const uint4*)(outg + (size_t)NTOK * D_ + i);
    const unsigned* a = (const unsigned*)&u0;
    const unsigned* b = (const unsigned*)&u1;
    float o[8];
    #pragma unroll
    for (int k = 0; k < 4; ++k) {
        o[2*k]   = __uint_as_float(a[k] << 16) + __uint_as_float(b[k] << 16);
        o[2*k+1] = __uint_as_float(a[k] & 0xffff0000u)
                 + __uint_as_float(b[k] & 0xffff0000u);
    }
    *(f32x4*)(out + i)     = *(f32x4*)(o);
    *(f32x4*)(out + i + 4) = *(f32x4*)(o + 4);
}

// ---------------------------------------------------------------------------
// Launch
// ---------------------------------------------------------------------------
extern "C" void kernel_launch(void* const* d_in, const int* in_sizes, int n_in,
                              void* d_out, int out_size, void* d_ws, size_t ws_size,
                              hipStream_t stream) {
    const float* x   = (const float*)d_in[0];
    const float* eps = (const float*)d_in[1];
    const float* Wr  = (const float*)d_in[2];
    const float* br  = (const float*)d_in[3];
    const float* Wn  = (const float*)d_in[4];
    const float* bn  = (const float*)d_in[5];
    const float* Wk  = (const float*)d_in[6];
    const float* bk  = (const float*)d_in[7];
    float* out = (float*)d_out;

    // workspace layout (256B-aligned)
    char* ws = (char*)d_ws;
    size_t off = 0;
    int* counts = (int*)(ws + off);                     off += 256;
    uint2* entries = (uint2*)(ws + off);                off += (size_t)E_ * CAP * 8;      // 1 MiB
    __hip_bfloat16* xb = (__hip_bfloat16*)(ws + off);   off += (size_t)NTOK * D_ * 2;     // 16 MiB
    __hip_bfloat16* wkt = (__hip_bfloat16*)(ws + off);  off += (size_t)E_ * D_ * D_ * 2;  // 4 MiB
    uint4* top2 = (uint4*)(ws + off);                   off += (size_t)NTOK * 16;         // 256 KiB
    __hip_bfloat16* outg = (__hip_bfloat16*)(ws + off); off += (size_t)2 * NTOK * D_ * 2; // 32 MiB
    const int use_slots = (ws_size >= off) ? 1 : 0;

    hipMemsetAsync(counts, 0, E_ * sizeof(int), stream);
    if (!use_slots)
        hipMemsetAsync(out, 0, (size_t)out_size * sizeof(float), stream);

    transpose_wk<<<dim3(16, 16, E_), dim3(32, 8), 0, stream>>>(Wk, wkt);
    router_kernel<<<dim3(NTOK / RV_TOK), dim3(RV_THR), 0, stream>>>(
        x, eps, Wr, br, Wn, bn, xb, top2);
    bucket_kernel<<<dim3(NTOK / 256), dim3(256), 0, stream>>>(top2, counts, entries);
    moe_gemm<<<dim3(D_ / 128, CAP / 128, E_), dim3(256), 0, stream>>>(
        xb, wkt, bk, counts, entries, outg, out, use_slots);
    if (use_slots)
        combine_kernel<<<dim3((NTOK * D_) / (256 * 8)), dim3(256), 0, stream>>>(outg, out);
}